// Round 11
// baseline (61.009 us; speedup 1.0000x reference)
//
#include <hip/hip_runtime.h>
#include <hip/hip_bf16.h>

#define D_N 512
#define M_N 1024
#define F_N 64
#define L2E 1.442695041f

__device__ __forceinline__ float wred_sum(float p) {
#pragma unroll
    for (int off = 32; off > 0; off >>= 1) p += __shfl_xor(p, off, 64);
    return p;
}

// q[lane] = sum_k att[k] * W[k][lane]  (one wave)
__device__ __forceinline__ float proj_col(const float* __restrict__ gw,
                                          const float* __restrict__ att,
                                          int lane) {
    float acc = 0.f;
#pragma unroll
    for (int k = 0; k < 64; ++k)
        acc += att[k] * gw[k * 64 + lane];
    return acc;
}

// ---------------------------------------------------------------------------
// n1 kprep (64 blocks x 512):
//  b 0..15 : c-gathers rows [b*32,+32): pp P0[b], MC[16+b]; uc[row] dots
//  b 16..47: m-gathers: pp P1[32+g2], MM[64+g2]; umed dots
//  b 48..63: hattr dots -> v[row]
// ---------------------------------------------------------------------------
__global__ __launch_bounds__(512) void kprep(
    const int* __restrict__ c_it, const int* __restrict__ m_it,
    const float* __restrict__ c_emb, const float* __restrict__ m_emb,
    const float* __restrict__ pe0, const float* __restrict__ pe1,
    const float* __restrict__ gat_w, const float* __restrict__ gat_att,
    const float* __restrict__ hattr,
    float* __restrict__ umed, float* __restrict__ uc, float* __restrict__ v,
    float* __restrict__ pp)
{
    __shared__ __align__(16) float qs[64];
    __shared__ float redA[8][64], redB[8][64];
    const int b = blockIdx.x, tid = threadIdx.x;
    const int w = tid >> 6, lane = tid & 63;

    if (b < 48) {
        if (w == 0) qs[lane] = proj_col(gat_w, gat_att, lane);   // q1
        __syncthreads();
        const int* idx; const float* ta; const float* tb;
        float* dout; int base_r, oA, oB;
        if (b < 16) { idx = c_it; ta = pe0; tb = c_emb; dout = uc;
                      base_r = b * 32; oA = b; oB = 16 + b; }
        else { int g2 = b - 16; idx = m_it; ta = pe1; tb = m_emb; dout = umed;
               base_r = g2 * 32; oA = 32 + g2; oB = 64 + g2; }
        const int r0 = base_r + w * 4;
        float a = 0.f, bb = 0.f;
#pragma unroll
        for (int j = 0; j < 4; ++j) {
            const int row = r0 + j;
            const int r = idx[row];
            float av = ta[(size_t)r * F_N + lane];
            float bv = tb[(size_t)r * F_N + lane];
            a += av; bb += bv;
            float d = wred_sum(bv * qs[lane]);
            if (lane == 0) dout[row] = L2E * d;
        }
        redA[w][lane] = a; redB[w][lane] = bb;
        __syncthreads();
        if (w == 0) {
            float sa = 0.f, sbv = 0.f;
#pragma unroll
            for (int i = 0; i < 8; ++i) { sa += redA[i][lane]; sbv += redB[i][lane]; }
            pp[oA * 64 + lane] = sa;
            pp[oB * 64 + lane] = sbv;
        }
    } else {
        if (w == 0) qs[lane] = proj_col(gat_w, gat_att + 64, lane);  // q2
        __syncthreads();
        const int r0 = (b - 48) * 32 + w * 4;
#pragma unroll
        for (int j = 0; j < 4; ++j) {
            const int row = r0 + j;
            float hv = hattr[(size_t)row * F_N + lane];
            float d = wred_sum(hv * qs[lane]);
            if (lane == 0) v[row] = L2E * d;
        }
    }
}

// ---------------------------------------------------------------------------
// n2 kcomb (36 blocks x 512): stages umed/uc/v in LDS, then
//  blocks 0..31 (med): per-THREAD recompute of its edge's softmax scalars
//    (pure VALU, LDS-broadcast reads) -> sC1/sC2; g-weights for 32 meds;
//    embedding-space weighted sums -> e1p/e2p[b].
//  blocks 32..35 (self): wave-per-edge denominators (16 edges/wave),
//    self-term partials -> e1dp/e2dp[b-32].
// ---------------------------------------------------------------------------
__global__ __launch_bounds__(512) void kcomb(
    const int* __restrict__ c_it, const int* __restrict__ m_it,
    const float* __restrict__ c_emb, const float* __restrict__ m_emb,
    const float* __restrict__ umed_g, const float* __restrict__ uc_g,
    const float* __restrict__ v_g,
    float* __restrict__ e1p, float* __restrict__ e2p,
    float* __restrict__ e1dp, float* __restrict__ e2dp)
{
    __shared__ __align__(16) float umed[M_N];
    __shared__ float sUc[D_N], sV[D_N];
    __shared__ float sC1[D_N], sC2[D_N];
    __shared__ float sG1[32], sG2[32];
    __shared__ float redA[8][64], redB[8][64];
    const int b = blockIdx.x, tid = threadIdx.x;
    const int w = tid >> 6, lane = tid & 63;

    umed[tid] = umed_g[tid];
    umed[tid + 512] = umed_g[tid + 512];
    sUc[tid] = uc_g[tid];
    sV[tid] = v_g[tid];
    __syncthreads();

    if (b < 32) {
        // ---- per-thread edge scalars: thread t owns edge t ----
        {
            const float ve = sV[tid];
            const float4* u4 = (const float4*)umed;
            float s = 0.f;
#pragma unroll 8
            for (int i = 0; i < 256; ++i) {
                float4 uv = u4[i];
                float a0 = uv.x + ve; a0 = fmaxf(a0, 0.2f * a0); s += exp2f(a0);
                float a1 = uv.y + ve; a1 = fmaxf(a1, 0.2f * a1); s += exp2f(a1);
                float a2 = uv.z + ve; a2 = fmaxf(a2, 0.2f * a2); s += exp2f(a2);
                float a3 = uv.w + ve; a3 = fmaxf(a3, 0.2f * a3); s += exp2f(a3);
            }
            float asf = sUc[tid] + ve; asf = fmaxf(asf, 0.2f * asf);
            const float exs = exp2f(asf);
            const float denom = s + exs;
            const float asel = exs / denom;
            const float rd = 1.f / (denom * (float)(M_N + 1));
            sC1[tid] = asel * rd;
            sC2[tid] = (1.f - asel) * rd;
        }
        __syncthreads();
        // ---- g-weights: 32 meds, 16 threads/med over 512 edges ----
        const int m_base = b * 32;
        {
            const int mi = tid >> 4, l16 = tid & 15;
            const float um = umed[m_base + mi];
            float gA = 0.f, gB = 0.f;
#pragma unroll 4
            for (int i = 0; i < 32; ++i) {
                int e = l16 + i * 16;
                float a = um + sV[e];
                a = fmaxf(a, 0.2f * a);
                float ex = exp2f(a);
                gA += sC1[e] * ex;
                gB += sC2[e] * ex;
            }
#pragma unroll
            for (int off = 1; off < 16; off <<= 1) {
                gA += __shfl_xor(gA, off, 64);
                gB += __shfl_xor(gB, off, 64);
            }
            if (l16 == 0) { sG1[mi] = gA; sG2[mi] = gB; }
        }
        __syncthreads();
        // ---- embedding-space weighted sums (8 waves x 4 meds) ----
        float a1 = 0.f, a2 = 0.f;
#pragma unroll
        for (int j = 0; j < 4; ++j) {
            int ml = w * 4 + j;
            float x = m_emb[(size_t)m_it[m_base + ml] * F_N + lane];
            a1 += sG1[ml] * x;
            a2 += sG2[ml] * x;
        }
        redA[w][lane] = a1; redB[w][lane] = a2;
        __syncthreads();
        if (w == 0) {
            float sa = 0.f, sbv = 0.f;
#pragma unroll
            for (int i = 0; i < 8; ++i) { sa += redA[i][lane]; sbv += redB[i][lane]; }
            e1p[b * 64 + lane] = sa;
            e2p[b * 64 + lane] = sbv;
        }
    } else {
        // ---- self blocks: 128 edges each, wave handles 16 serially ----
        const int sbb = b - 32;
        float accA = 0.f, accB = 0.f;
#pragma unroll 2
        for (int ee = 0; ee < 16; ++ee) {
            const int e = sbb * 128 + w * 16 + ee;
            const float ve = sV[e];
            float s = 0.f;
#pragma unroll
            for (int i = 0; i < 16; ++i) {
                float a = umed[i * 64 + lane] + ve;
                a = fmaxf(a, 0.2f * a);
                s += exp2f(a);
            }
            s = wred_sum(s);
            float asf = sUc[e] + ve; asf = fmaxf(asf, 0.2f * asf);
            const float exs = exp2f(asf);
            const float denom = s + exs;
            const float asel = exs / denom;
            const float rd = 1.f / (denom * (float)(M_N + 1));
            const float w1a = asel * rd * exs;
            const float w2a = (1.f - asel) * rd * exs;
            const float xe = c_emb[(size_t)c_it[e] * F_N + lane];
            accA += w1a * xe;
            accB += w2a * xe;
        }
        redA[w][lane] = accA; redB[w][lane] = accB;
        __syncthreads();
        if (w == 0) {
            float sa = 0.f, sbv = 0.f;
#pragma unroll
            for (int i = 0; i < 8; ++i) { sa += redA[i][lane]; sbv += redB[i][lane]; }
            e1dp[sbb * 64 + lane] = sa;
            e2dp[sbb * 64 + lane] = sbv;
        }
    }
}

// ---------------------------------------------------------------------------
// n3 kfin: single-block finisher.
// ---------------------------------------------------------------------------
__global__ __launch_bounds__(256) void kfin(
    const float* __restrict__ conv_w, const float* __restrict__ conv_b,
    const float* __restrict__ gat_w, const float* __restrict__ gat_b,
    const float* __restrict__ lin_w,
    const float* __restrict__ pp,
    const float* __restrict__ e1p, const float* __restrict__ e2p,
    const float* __restrict__ e1dp, const float* __restrict__ e2dp,
    float* __restrict__ out)
{
    __shared__ float sE1[64], sE2[64], sP0[64], sP1[64], sMC[64], sMM[64];
    __shared__ float sS1[64], sS2[64];
    __shared__ float sRepD[128], sRepM[128];
    __shared__ float sWt[64 * 65];
    __shared__ float sLt[128 * 65];
    const int tid = threadIdx.x, w = tid >> 6, lane = tid & 63;

    if (w == 0) {
        float a = 0.f;
#pragma unroll
        for (int i = 0; i < 32; ++i) a += e1p[i * 64 + lane];
#pragma unroll
        for (int i = 0; i < 4; ++i) a += e1dp[i * 64 + lane];
        sE1[lane] = a;
    } else if (w == 1) {
        float a = 0.f;
#pragma unroll
        for (int i = 0; i < 32; ++i) a += e2p[i * 64 + lane];
#pragma unroll
        for (int i = 0; i < 4; ++i) a += e2dp[i * 64 + lane];
        sE2[lane] = a;
    } else if (w == 2) {
        float a = 0.f, c = 0.f;
#pragma unroll
        for (int i = 0; i < 16; ++i) { a += pp[i * 64 + lane]; c += pp[(16 + i) * 64 + lane]; }
        sP0[lane] = a; sMC[lane] = c * (1.f / (float)D_N);
    } else {
        float a = 0.f, c = 0.f;
#pragma unroll
        for (int i = 0; i < 32; ++i) { a += pp[(32 + i) * 64 + lane]; c += pp[(64 + i) * 64 + lane]; }
        sP1[lane] = a; sMM[lane] = c * (1.f / (float)M_N);
    }
    for (int i = tid; i < 4096; i += 256)
        sWt[(i & 63) * 65 + (i >> 6)] = gat_w[i];          // sWt[j*65+k]=W[k][j]
    for (int i = tid; i < 8192; i += 256) {
        int k = i >> 7, j = i & 127;
        sLt[j * 65 + k] = lin_w[i];                        // sLt[j*65+k]=lin_w[k][j]
    }
    __syncthreads();
    if (tid < 64) {
        float s1 = 0.f, s2 = 0.f;
#pragma unroll 8
        for (int j = 0; j < 64; ++j) {
            s1 += sE1[j] * sWt[j * 65 + lane];
            s2 += sE2[j] * sWt[j * 65 + lane];
        }
        sS1[lane] = s1;
        sS2[lane] = s2 * (1.f / (float)D_N);
    }
    __syncthreads();
    for (int i = tid; i < 4096; i += 256)
        sWt[(i & 63) * 65 + (i >> 6)] = conv_w[i];
    __syncthreads();
    if (tid < 64) {
        float dia = conv_b[lane], med = conv_b[lane];
#pragma unroll 8
        for (int j = 0; j < 64; ++j) {
            dia += sMC[j] * sWt[j * 65 + lane];
            med += sMM[j] * sWt[j * 65 + lane];
        }
        sRepD[lane]      = sS1[lane] + (float)D_N * gat_b[lane];
        sRepD[64 + lane] = (float)D_N * dia;
        sRepM[lane]      = sS2[lane] + (float)M_N * gat_b[lane];
        sRepM[64 + lane] = (float)M_N * med;
    }
    __syncthreads();
    if (tid < 64) {
        float o1 = sP0[lane], o2 = sP1[lane];
#pragma unroll 8
        for (int j = 0; j < 128; ++j) {
            o1 += sRepD[j] * sLt[j * 65 + lane];
            o2 += sRepM[j] * sLt[j * 65 + lane];
        }
        out[lane] = o1;
        out[64 + lane] = o2;
    }
}

extern "C" void kernel_launch(void* const* d_in, const int* in_sizes, int n_in,
                              void* d_out, int out_size, void* d_ws, size_t ws_size,
                              hipStream_t stream) {
    const int*   c_it    = (const int*)d_in[0];
    const int*   m_it    = (const int*)d_in[1];
    const float* c_emb   = (const float*)d_in[2];
    const float* m_emb   = (const float*)d_in[3];
    const float* pe0     = (const float*)d_in[4];
    const float* pe1     = (const float*)d_in[5];
    const float* conv_w  = (const float*)d_in[6];
    const float* conv_b  = (const float*)d_in[7];
    const float* gat_w   = (const float*)d_in[8];
    const float* gat_b   = (const float*)d_in[9];
    const float* gat_att = (const float*)d_in[10];
    const float* hattr   = (const float*)d_in[11];
    const float* lin_w   = (const float*)d_in[12];
    float* out = (float*)d_out;

    float* ws   = (float*)d_ws;
    float* umed = ws;                 // 1024
    float* uc   = umed + M_N;         // 512
    float* v    = uc + D_N;           // 512
    float* pp   = v + D_N;            // 96*64
    float* e1p  = pp + 96 * 64;       // 32*64
    float* e2p  = e1p + 32 * 64;      // 32*64
    float* e1dp = e2p + 32 * 64;      // 4*64
    float* e2dp = e1dp + 4 * 64;      // 4*64

    kprep<<<64, 512, 0, stream>>>(c_it, m_it, c_emb, m_emb, pe0, pe1,
                                  gat_w, gat_att, hattr, umed, uc, v, pp);
    kcomb<<<36, 512, 0, stream>>>(c_it, m_it, c_emb, m_emb,
                                  umed, uc, v, e1p, e2p, e1dp, e2dp);
    kfin<<<1, 256, 0, stream>>>(conv_w, conv_b, gat_w, gat_b, lin_w,
                                pp, e1p, e2p, e1dp, e2dp, out);
}

// Round 12
// 24.837 us; speedup vs baseline: 2.4563x; 2.4563x over previous
//
#include <hip/hip_runtime.h>
#include <hip/hip_bf16.h>

#define D_N 512
#define M_N 1024
#define F_N 64
#define L2E 1.442695041f

__device__ __forceinline__ float wred_sum(float p) {
#pragma unroll
    for (int off = 32; off > 0; off >>= 1) p += __shfl_xor(p, off, 64);
    return p;
}

// q[lane] = sum_k att[k] * W[k][lane]  (one wave)
__device__ __forceinline__ float proj_col(const float* __restrict__ gw,
                                          const float* __restrict__ att,
                                          int lane) {
    float acc = 0.f;
#pragma unroll
    for (int k = 0; k < 64; ++k)
        acc += att[k] * gw[k * 64 + lane];
    return acc;
}

// ---------------------------------------------------------------------------
// n1 kprep (64 blocks x 512):
//  b 0..15 : c-gathers rows [b*32,+32): pp P0[b], MC[16+b]; uc[row] dots
//  b 16..47: m-gathers: pp P1[32+g2], MM[64+g2]; umed dots
//  b 48..63: hattr dots -> v[row]
// ---------------------------------------------------------------------------
__global__ __launch_bounds__(512) void kprep(
    const int* __restrict__ c_it, const int* __restrict__ m_it,
    const float* __restrict__ c_emb, const float* __restrict__ m_emb,
    const float* __restrict__ pe0, const float* __restrict__ pe1,
    const float* __restrict__ gat_w, const float* __restrict__ gat_att,
    const float* __restrict__ hattr,
    float* __restrict__ umed, float* __restrict__ uc, float* __restrict__ v,
    float* __restrict__ pp)
{
    __shared__ __align__(16) float qs[64];
    __shared__ float redA[8][64], redB[8][64];
    const int b = blockIdx.x, tid = threadIdx.x;
    const int w = tid >> 6, lane = tid & 63;

    if (b < 48) {
        if (w == 0) qs[lane] = proj_col(gat_w, gat_att, lane);   // q1
        __syncthreads();
        const int* idx; const float* ta; const float* tb;
        float* dout; int base_r, oA, oB;
        if (b < 16) { idx = c_it; ta = pe0; tb = c_emb; dout = uc;
                      base_r = b * 32; oA = b; oB = 16 + b; }
        else { int g2 = b - 16; idx = m_it; ta = pe1; tb = m_emb; dout = umed;
               base_r = g2 * 32; oA = 32 + g2; oB = 64 + g2; }
        const int r0 = base_r + w * 4;
        float a = 0.f, bb = 0.f;
#pragma unroll
        for (int j = 0; j < 4; ++j) {
            const int row = r0 + j;
            const int r = idx[row];
            float av = ta[(size_t)r * F_N + lane];
            float bv = tb[(size_t)r * F_N + lane];
            a += av; bb += bv;
            float d = wred_sum(bv * qs[lane]);
            if (lane == 0) dout[row] = L2E * d;
        }
        redA[w][lane] = a; redB[w][lane] = bb;
        __syncthreads();
        if (w == 0) {
            float sa = 0.f, sbv = 0.f;
#pragma unroll
            for (int i = 0; i < 8; ++i) { sa += redA[i][lane]; sbv += redB[i][lane]; }
            pp[oA * 64 + lane] = sa;
            pp[oB * 64 + lane] = sbv;
        }
    } else {
        if (w == 0) qs[lane] = proj_col(gat_w, gat_att + 64, lane);  // q2
        __syncthreads();
        const int r0 = (b - 48) * 32 + w * 4;
#pragma unroll
        for (int j = 0; j < 4; ++j) {
            const int row = r0 + j;
            float hv = hattr[(size_t)row * F_N + lane];
            float d = wred_sum(hv * qs[lane]);
            if (lane == 0) v[row] = L2E * d;
        }
    }
}

// ---------------------------------------------------------------------------
// n2 kedge (32 blocks x 512): 16 edges/block, wave handles 2 edges.
//  Per edge: softmax denominator over umed (LDS) -> c1f,c2f; accumulate
//  self-term partials e1dp/e2dp[b].
// ---------------------------------------------------------------------------
__global__ __launch_bounds__(512) void kedge(
    const int* __restrict__ c_it, const float* __restrict__ c_emb,
    const float* __restrict__ umed_g, const float* __restrict__ uc,
    const float* __restrict__ v,
    float* __restrict__ c1f, float* __restrict__ c2f,
    float* __restrict__ e1dp, float* __restrict__ e2dp)
{
    __shared__ float umed[M_N];
    __shared__ float redA[8][64], redB[8][64];
    const int b = blockIdx.x, tid = threadIdx.x;
    const int w = tid >> 6, lane = tid & 63;

    umed[tid] = umed_g[tid];
    umed[tid + 512] = umed_g[tid + 512];
    __syncthreads();

    float accA = 0.f, accB = 0.f;
#pragma unroll
    for (int ee = 0; ee < 2; ++ee) {
        const int e = b * 16 + w * 2 + ee;
        const float ve = v[e];
        float s = 0.f;
#pragma unroll
        for (int i = 0; i < 16; ++i) {
            float a = umed[i * 64 + lane] + ve;
            a = fmaxf(a, 0.2f * a);
            s += exp2f(a);
        }
        s = wred_sum(s);
        float asf = uc[e] + ve; asf = fmaxf(asf, 0.2f * asf);
        const float exs = exp2f(asf);
        const float denom = s + exs;
        const float asel = exs / denom;
        const float rd = 1.f / (denom * (float)(M_N + 1));
        if (lane == 0) {
            c1f[e] = asel * rd;
            c2f[e] = (1.f - asel) * rd;
        }
        const float w1a = asel * rd * exs;
        const float w2a = (1.f - asel) * rd * exs;
        const float xe = c_emb[(size_t)c_it[e] * F_N + lane];
        accA += w1a * xe;
        accB += w2a * xe;
    }
    redA[w][lane] = accA; redB[w][lane] = accB;
    __syncthreads();
    if (w == 0) {
        float sa = 0.f, sbv = 0.f;
#pragma unroll
        for (int i = 0; i < 8; ++i) { sa += redA[i][lane]; sbv += redB[i][lane]; }
        e1dp[b * 64 + lane] = sa;
        e2dp[b * 64 + lane] = sbv;
    }
}

// ---------------------------------------------------------------------------
// n3 kmed (32 blocks x 512): 32 meds/block. g1/g2 per med over 512 edges,
//  then embedding-space weighted sums -> e1p/e2p[b].
// ---------------------------------------------------------------------------
__global__ __launch_bounds__(512) void kmed(
    const int* __restrict__ m_it, const float* __restrict__ m_emb,
    const float* __restrict__ umed_g, const float* __restrict__ v,
    const float* __restrict__ c1f, const float* __restrict__ c2f,
    float* __restrict__ e1p, float* __restrict__ e2p)
{
    __shared__ float sV[D_N], sC1[D_N], sC2[D_N];
    __shared__ float sUm[32], sG1[32], sG2[32];
    __shared__ float redA[8][64], redB[8][64];
    const int b = blockIdx.x, tid = threadIdx.x;
    const int w = tid >> 6, lane = tid & 63;
    const int m_base = b * 32;

    sV[tid] = v[tid]; sC1[tid] = c1f[tid]; sC2[tid] = c2f[tid];
    if (tid < 32) sUm[tid] = umed_g[m_base + tid];
    __syncthreads();

    {
        const int mi = tid >> 4, l16 = tid & 15;
        const float um = sUm[mi];
        float gA = 0.f, gB = 0.f;
#pragma unroll 4
        for (int i = 0; i < 32; ++i) {
            int e = l16 + i * 16;
            float a = um + sV[e];
            a = fmaxf(a, 0.2f * a);
            float ex = exp2f(a);
            gA += sC1[e] * ex;
            gB += sC2[e] * ex;
        }
#pragma unroll
        for (int off = 1; off < 16; off <<= 1) {
            gA += __shfl_xor(gA, off, 64);
            gB += __shfl_xor(gB, off, 64);
        }
        if (l16 == 0) { sG1[mi] = gA; sG2[mi] = gB; }
    }
    __syncthreads();
    float a1 = 0.f, a2 = 0.f;
#pragma unroll
    for (int j = 0; j < 4; ++j) {
        int ml = w * 4 + j;
        float x = m_emb[(size_t)m_it[m_base + ml] * F_N + lane];
        a1 += sG1[ml] * x;
        a2 += sG2[ml] * x;
    }
    redA[w][lane] = a1; redB[w][lane] = a2;
    __syncthreads();
    if (w == 0) {
        float sa = 0.f, sbv = 0.f;
#pragma unroll
        for (int i = 0; i < 8; ++i) { sa += redA[i][lane]; sbv += redB[i][lane]; }
        e1p[b * 64 + lane] = sa;
        e2p[b * 64 + lane] = sbv;
    }
}

// ---------------------------------------------------------------------------
// n4 kfin (1 block x 512): parallel folds (7 waves), then matvecs.
// ---------------------------------------------------------------------------
__global__ __launch_bounds__(512) void kfin(
    const float* __restrict__ conv_w, const float* __restrict__ conv_b,
    const float* __restrict__ gat_w, const float* __restrict__ gat_b,
    const float* __restrict__ lin_w,
    const float* __restrict__ pp,
    const float* __restrict__ e1p, const float* __restrict__ e2p,
    const float* __restrict__ e1dp, const float* __restrict__ e2dp,
    float* __restrict__ out)
{
    __shared__ float pA[8][64], pB[8][64];
    __shared__ float sE1[64], sE2[64], sP0[64], sP1[64], sMC[64], sMM[64];
    __shared__ float sS1[64], sS2[64];
    __shared__ float sRepD[128], sRepM[128];
    __shared__ float sWt[64 * 65];
    __shared__ float sLt[128 * 65];
    const int tid = threadIdx.x, w = tid >> 6, lane = tid & 63;

    // parallel partial folds (each wave: <=32 serial loads)
    {
        float a = 0.f, bb = 0.f;
        switch (w) {
        case 0:
#pragma unroll
            for (int i = 0; i < 32; ++i) a += e1p[i * 64 + lane];
            break;
        case 1:
#pragma unroll
            for (int i = 0; i < 32; ++i) a += e1dp[i * 64 + lane];
            break;
        case 2:
#pragma unroll
            for (int i = 0; i < 32; ++i) a += e2p[i * 64 + lane];
            break;
        case 3:
#pragma unroll
            for (int i = 0; i < 32; ++i) a += e2dp[i * 64 + lane];
            break;
        case 4:
#pragma unroll
            for (int i = 0; i < 16; ++i) { a += pp[i * 64 + lane]; bb += pp[(16 + i) * 64 + lane]; }
            break;
        case 5:
#pragma unroll
            for (int i = 0; i < 32; ++i) a += pp[(32 + i) * 64 + lane];
            break;
        default:
#pragma unroll
            for (int i = 0; i < 32; ++i) a += pp[(64 + i) * 64 + lane];
            break;
        }
        pA[w][lane] = a; pB[w][lane] = bb;
    }
    for (int i = tid; i < 4096; i += 512)
        sWt[(i & 63) * 65 + (i >> 6)] = gat_w[i];          // sWt[j*65+k]=W[k][j]
    for (int i = tid; i < 8192; i += 512) {
        int k = i >> 7, j = i & 127;
        sLt[j * 65 + k] = lin_w[i];                        // sLt[j*65+k]=lin_w[k][j]
    }
    __syncthreads();
    if (w == 0) {
        sE1[lane] = pA[0][lane] + pA[1][lane];
        sE2[lane] = pA[2][lane] + pA[3][lane];
        sP0[lane] = pA[4][lane];
        sMC[lane] = pB[4][lane] * (1.f / (float)D_N);
        sP1[lane] = pA[5][lane];
        sMM[lane] = pA[6][lane] * (1.f / (float)M_N);
    }
    __syncthreads();
    if (tid < 64) {
        float s1 = 0.f, s2 = 0.f;
#pragma unroll 8
        for (int j = 0; j < 64; ++j) {
            s1 += sE1[j] * sWt[j * 65 + lane];
            s2 += sE2[j] * sWt[j * 65 + lane];
        }
        sS1[lane] = s1;
        sS2[lane] = s2 * (1.f / (float)D_N);
    }
    __syncthreads();
    for (int i = tid; i < 4096; i += 512)
        sWt[(i & 63) * 65 + (i >> 6)] = conv_w[i];
    __syncthreads();
    if (tid < 64) {
        float dia = conv_b[lane], med = conv_b[lane];
#pragma unroll 8
        for (int j = 0; j < 64; ++j) {
            dia += sMC[j] * sWt[j * 65 + lane];
            med += sMM[j] * sWt[j * 65 + lane];
        }
        sRepD[lane]      = sS1[lane] + (float)D_N * gat_b[lane];
        sRepD[64 + lane] = (float)D_N * dia;
        sRepM[lane]      = sS2[lane] + (float)M_N * gat_b[lane];
        sRepM[64 + lane] = (float)M_N * med;
    }
    __syncthreads();
    if (tid < 64) {
        float o1 = sP0[lane], o2 = sP1[lane];
#pragma unroll 8
        for (int j = 0; j < 128; ++j) {
            o1 += sRepD[j] * sLt[j * 65 + lane];
            o2 += sRepM[j] * sLt[j * 65 + lane];
        }
        out[lane] = o1;
        out[64 + lane] = o2;
    }
}

extern "C" void kernel_launch(void* const* d_in, const int* in_sizes, int n_in,
                              void* d_out, int out_size, void* d_ws, size_t ws_size,
                              hipStream_t stream) {
    const int*   c_it    = (const int*)d_in[0];
    const int*   m_it    = (const int*)d_in[1];
    const float* c_emb   = (const float*)d_in[2];
    const float* m_emb   = (const float*)d_in[3];
    const float* pe0     = (const float*)d_in[4];
    const float* pe1     = (const float*)d_in[5];
    const float* conv_w  = (const float*)d_in[6];
    const float* conv_b  = (const float*)d_in[7];
    const float* gat_w   = (const float*)d_in[8];
    const float* gat_b   = (const float*)d_in[9];
    const float* gat_att = (const float*)d_in[10];
    const float* hattr   = (const float*)d_in[11];
    const float* lin_w   = (const float*)d_in[12];
    float* out = (float*)d_out;

    float* ws   = (float*)d_ws;
    float* umed = ws;                 // 1024
    float* uc   = umed + M_N;         // 512
    float* v    = uc + D_N;           // 512
    float* c1f  = v + D_N;            // 512
    float* c2f  = c1f + D_N;          // 512
    float* pp   = c2f + D_N;          // 96*64
    float* e1p  = pp + 96 * 64;       // 32*64
    float* e2p  = e1p + 32 * 64;      // 32*64
    float* e1dp = e2p + 32 * 64;      // 32*64
    float* e2dp = e1dp + 32 * 64;     // 32*64

    kprep<<<64, 512, 0, stream>>>(c_it, m_it, c_emb, m_emb, pe0, pe1,
                                  gat_w, gat_att, hattr, umed, uc, v, pp);
    kedge<<<32, 512, 0, stream>>>(c_it, c_emb, umed, uc, v,
                                  c1f, c2f, e1dp, e2dp);
    kmed<<<32, 512, 0, stream>>>(m_it, m_emb, umed, v, c1f, c2f, e1p, e2p);
    kfin<<<1, 512, 0, stream>>>(conv_w, conv_b, gat_w, gat_b, lin_w,
                                pp, e1p, e2p, e1dp, e2dp, out);
}

// Round 13
// 23.779 us; speedup vs baseline: 2.5656x; 1.0445x over previous
//
#include <hip/hip_runtime.h>
#include <hip/hip_bf16.h>

#define D_N 512
#define M_N 1024
#define F_N 64
#define L2E 1.442695041f

__device__ __forceinline__ float wred_sum(float p) {
#pragma unroll
    for (int off = 32; off > 0; off >>= 1) p += __shfl_xor(p, off, 64);
    return p;
}

// q[lane] = sum_k att[k] * W[k][lane]  (one wave)
__device__ __forceinline__ float proj_col(const float* __restrict__ gw,
                                          const float* __restrict__ att,
                                          int lane) {
    float acc = 0.f;
#pragma unroll
    for (int k = 0; k < 64; ++k)
        acc += att[k] * gw[k * 64 + lane];
    return acc;
}

// ---------------------------------------------------------------------------
// n1 kprep (128 blocks x 512): 2 rows per wave (shortest chains)
//  b 0..31  : c-gathers rows [b*16,+16): pp P0[b], MC[32+b]; uc dots
//  b 32..95 : m-gathers rows [(b-32)*16,+16): pp P1[64+g2], MM[128+g2]; umed dots
//  b 96..127: hattr dots -> v
//  pp layout: P0 [0,32) MC [32,64) P1 [64,128) MM [128,192)
// ---------------------------------------------------------------------------
__global__ __launch_bounds__(512) void kprep(
    const int* __restrict__ c_it, const int* __restrict__ m_it,
    const float* __restrict__ c_emb, const float* __restrict__ m_emb,
    const float* __restrict__ pe0, const float* __restrict__ pe1,
    const float* __restrict__ gat_w, const float* __restrict__ gat_att,
    const float* __restrict__ hattr,
    float* __restrict__ umed, float* __restrict__ uc, float* __restrict__ v,
    float* __restrict__ pp)
{
    __shared__ __align__(16) float qs[64];
    __shared__ float redA[8][64], redB[8][64];
    const int b = blockIdx.x, tid = threadIdx.x;
    const int w = tid >> 6, lane = tid & 63;

    if (b < 96) {
        if (w == 0) qs[lane] = proj_col(gat_w, gat_att, lane);   // q1
        __syncthreads();
        const int* idx; const float* ta; const float* tb;
        float* dout; int base_r, oA, oB;
        if (b < 32) { idx = c_it; ta = pe0; tb = c_emb; dout = uc;
                      base_r = b * 16; oA = b; oB = 32 + b; }
        else { int g2 = b - 32; idx = m_it; ta = pe1; tb = m_emb; dout = umed;
               base_r = g2 * 16; oA = 64 + g2; oB = 128 + g2; }
        const int r0 = base_r + w * 2;
        float a = 0.f, bb = 0.f;
#pragma unroll
        for (int j = 0; j < 2; ++j) {
            const int row = r0 + j;
            const int r = idx[row];
            float av = ta[(size_t)r * F_N + lane];
            float bv = tb[(size_t)r * F_N + lane];
            a += av; bb += bv;
            float d = wred_sum(bv * qs[lane]);
            if (lane == 0) dout[row] = L2E * d;
        }
        redA[w][lane] = a; redB[w][lane] = bb;
        __syncthreads();
        if (w == 0) {
            float sa = 0.f, sbv = 0.f;
#pragma unroll
            for (int i = 0; i < 8; ++i) { sa += redA[i][lane]; sbv += redB[i][lane]; }
            pp[oA * 64 + lane] = sa;
            pp[oB * 64 + lane] = sbv;
        }
    } else {
        if (w == 0) qs[lane] = proj_col(gat_w, gat_att + 64, lane);  // q2
        __syncthreads();
        const int r0 = (b - 96) * 16 + w * 2;
#pragma unroll
        for (int j = 0; j < 2; ++j) {
            const int row = r0 + j;
            float hv = hattr[(size_t)row * F_N + lane];
            float d = wred_sum(hv * qs[lane]);
            if (lane == 0) v[row] = L2E * d;
        }
    }
}

// ---------------------------------------------------------------------------
// n2 kedge (64 blocks x 512): 8 edges/block, ONE edge per wave.
//  Per edge: softmax denominator over umed (LDS) -> c1f,c2f; self-term
//  partials e1dp/e2dp[b].
// ---------------------------------------------------------------------------
__global__ __launch_bounds__(512) void kedge(
    const int* __restrict__ c_it, const float* __restrict__ c_emb,
    const float* __restrict__ umed_g, const float* __restrict__ uc,
    const float* __restrict__ v,
    float* __restrict__ c1f, float* __restrict__ c2f,
    float* __restrict__ e1dp, float* __restrict__ e2dp)
{
    __shared__ float umed[M_N];
    __shared__ float redA[8][64], redB[8][64];
    const int b = blockIdx.x, tid = threadIdx.x;
    const int w = tid >> 6, lane = tid & 63;

    umed[tid] = umed_g[tid];
    umed[tid + 512] = umed_g[tid + 512];
    __syncthreads();

    const int e = b * 8 + w;
    const float ve = v[e];
    float s = 0.f;
#pragma unroll
    for (int i = 0; i < 16; ++i) {
        float a = umed[i * 64 + lane] + ve;
        a = fmaxf(a, 0.2f * a);
        s += exp2f(a);
    }
    s = wred_sum(s);
    float asf = uc[e] + ve; asf = fmaxf(asf, 0.2f * asf);
    const float exs = exp2f(asf);
    const float denom = s + exs;
    const float asel = exs / denom;
    const float rd = 1.f / (denom * (float)(M_N + 1));
    if (lane == 0) {
        c1f[e] = asel * rd;
        c2f[e] = (1.f - asel) * rd;
    }
    const float w1a = asel * rd * exs;
    const float w2a = (1.f - asel) * rd * exs;
    const float xe = c_emb[(size_t)c_it[e] * F_N + lane];
    redA[w][lane] = w1a * xe;
    redB[w][lane] = w2a * xe;
    __syncthreads();
    if (w == 0) {
        float sa = 0.f, sbv = 0.f;
#pragma unroll
        for (int i = 0; i < 8; ++i) { sa += redA[i][lane]; sbv += redB[i][lane]; }
        e1dp[b * 64 + lane] = sa;
        e2dp[b * 64 + lane] = sbv;
    }
}

// ---------------------------------------------------------------------------
// n3 kmed (64 blocks x 512): 16 meds/block, 32 threads/med (16 serial e-iters).
//  g1/g2 per med, then embedding-space weighted sums -> e1p/e2p[b].
// ---------------------------------------------------------------------------
__global__ __launch_bounds__(512) void kmed(
    const int* __restrict__ m_it, const float* __restrict__ m_emb,
    const float* __restrict__ umed_g, const float* __restrict__ v,
    const float* __restrict__ c1f, const float* __restrict__ c2f,
    float* __restrict__ e1p, float* __restrict__ e2p)
{
    __shared__ float sV[D_N], sC1[D_N], sC2[D_N];
    __shared__ float sUm[16], sG1[16], sG2[16];
    __shared__ float redA[8][64], redB[8][64];
    const int b = blockIdx.x, tid = threadIdx.x;
    const int w = tid >> 6, lane = tid & 63;
    const int m_base = b * 16;

    sV[tid] = v[tid]; sC1[tid] = c1f[tid]; sC2[tid] = c2f[tid];
    if (tid < 16) sUm[tid] = umed_g[m_base + tid];
    __syncthreads();

    {
        const int mi = tid >> 5, l32 = tid & 31;
        const float um = sUm[mi];
        float gA = 0.f, gB = 0.f;
#pragma unroll 4
        for (int i = 0; i < 16; ++i) {
            int e = l32 + i * 32;
            float a = um + sV[e];
            a = fmaxf(a, 0.2f * a);
            float ex = exp2f(a);
            gA += sC1[e] * ex;
            gB += sC2[e] * ex;
        }
#pragma unroll
        for (int off = 1; off < 32; off <<= 1) {
            gA += __shfl_xor(gA, off, 64);
            gB += __shfl_xor(gB, off, 64);
        }
        if (l32 == 0) { sG1[mi] = gA; sG2[mi] = gB; }
    }
    __syncthreads();
    float a1 = 0.f, a2 = 0.f;
#pragma unroll
    for (int j = 0; j < 2; ++j) {
        int ml = w * 2 + j;
        float x = m_emb[(size_t)m_it[m_base + ml] * F_N + lane];
        a1 += sG1[ml] * x;
        a2 += sG2[ml] * x;
    }
    redA[w][lane] = a1; redB[w][lane] = a2;
    __syncthreads();
    if (w == 0) {
        float sa = 0.f, sbv = 0.f;
#pragma unroll
        for (int i = 0; i < 8; ++i) { sa += redA[i][lane]; sbv += redB[i][lane]; }
        e1p[b * 64 + lane] = sa;
        e2p[b * 64 + lane] = sbv;
    }
}

// ---------------------------------------------------------------------------
// n4 kfin (1 block x 512): parallel folds (7 waves, independent loads),
//  then matvecs.
// ---------------------------------------------------------------------------
__global__ __launch_bounds__(512) void kfin(
    const float* __restrict__ conv_w, const float* __restrict__ conv_b,
    const float* __restrict__ gat_w, const float* __restrict__ gat_b,
    const float* __restrict__ lin_w,
    const float* __restrict__ pp,
    const float* __restrict__ e1p, const float* __restrict__ e2p,
    const float* __restrict__ e1dp, const float* __restrict__ e2dp,
    float* __restrict__ out)
{
    __shared__ float pA[8][64], pB[8][64];
    __shared__ float sE1[64], sE2[64], sP0[64], sP1[64], sMC[64], sMM[64];
    __shared__ float sS1[64], sS2[64];
    __shared__ float sRepD[128], sRepM[128];
    __shared__ float sWt[64 * 65];
    __shared__ float sLt[128 * 65];
    const int tid = threadIdx.x, w = tid >> 6, lane = tid & 63;

    {
        float a = 0.f, bb = 0.f;
        switch (w) {
        case 0:
#pragma unroll
            for (int i = 0; i < 64; ++i) a += e1p[i * 64 + lane];
            break;
        case 1:
#pragma unroll
            for (int i = 0; i < 64; ++i) a += e1dp[i * 64 + lane];
            break;
        case 2:
#pragma unroll
            for (int i = 0; i < 64; ++i) a += e2p[i * 64 + lane];
            break;
        case 3:
#pragma unroll
            for (int i = 0; i < 64; ++i) a += e2dp[i * 64 + lane];
            break;
        case 4:
#pragma unroll
            for (int i = 0; i < 32; ++i) { a += pp[i * 64 + lane]; bb += pp[(32 + i) * 64 + lane]; }
            break;
        case 5:
#pragma unroll
            for (int i = 0; i < 64; ++i) a += pp[(64 + i) * 64 + lane];
            break;
        default:
#pragma unroll
            for (int i = 0; i < 64; ++i) a += pp[(128 + i) * 64 + lane];
            break;
        }
        pA[w][lane] = a; pB[w][lane] = bb;
    }
    for (int i = tid; i < 4096; i += 512)
        sWt[(i & 63) * 65 + (i >> 6)] = gat_w[i];          // sWt[j*65+k]=W[k][j]
    for (int i = tid; i < 8192; i += 512) {
        int k = i >> 7, j = i & 127;
        sLt[j * 65 + k] = lin_w[i];                        // sLt[j*65+k]=lin_w[k][j]
    }
    __syncthreads();
    if (w == 0) {
        sE1[lane] = pA[0][lane] + pA[1][lane];
        sE2[lane] = pA[2][lane] + pA[3][lane];
        sP0[lane] = pA[4][lane];
        sMC[lane] = pB[4][lane] * (1.f / (float)D_N);
        sP1[lane] = pA[5][lane];
        sMM[lane] = pA[6][lane] * (1.f / (float)M_N);
    }
    __syncthreads();
    if (tid < 64) {
        float s1 = 0.f, s2 = 0.f;
#pragma unroll 8
        for (int j = 0; j < 64; ++j) {
            s1 += sE1[j] * sWt[j * 65 + lane];
            s2 += sE2[j] * sWt[j * 65 + lane];
        }
        sS1[lane] = s1;
        sS2[lane] = s2 * (1.f / (float)D_N);
    }
    __syncthreads();
    for (int i = tid; i < 4096; i += 512)
        sWt[(i & 63) * 65 + (i >> 6)] = conv_w[i];
    __syncthreads();
    if (tid < 64) {
        float dia = conv_b[lane], med = conv_b[lane];
#pragma unroll 8
        for (int j = 0; j < 64; ++j) {
            dia += sMC[j] * sWt[j * 65 + lane];
            med += sMM[j] * sWt[j * 65 + lane];
        }
        sRepD[lane]      = sS1[lane] + (float)D_N * gat_b[lane];
        sRepD[64 + lane] = (float)D_N * dia;
        sRepM[lane]      = sS2[lane] + (float)M_N * gat_b[lane];
        sRepM[64 + lane] = (float)M_N * med;
    }
    __syncthreads();
    if (tid < 64) {
        float o1 = sP0[lane], o2 = sP1[lane];
#pragma unroll 8
        for (int j = 0; j < 128; ++j) {
            o1 += sRepD[j] * sLt[j * 65 + lane];
            o2 += sRepM[j] * sLt[j * 65 + lane];
        }
        out[lane] = o1;
        out[64 + lane] = o2;
    }
}

extern "C" void kernel_launch(void* const* d_in, const int* in_sizes, int n_in,
                              void* d_out, int out_size, void* d_ws, size_t ws_size,
                              hipStream_t stream) {
    const int*   c_it    = (const int*)d_in[0];
    const int*   m_it    = (const int*)d_in[1];
    const float* c_emb   = (const float*)d_in[2];
    const float* m_emb   = (const float*)d_in[3];
    const float* pe0     = (const float*)d_in[4];
    const float* pe1     = (const float*)d_in[5];
    const float* conv_w  = (const float*)d_in[6];
    const float* conv_b  = (const float*)d_in[7];
    const float* gat_w   = (const float*)d_in[8];
    const float* gat_b   = (const float*)d_in[9];
    const float* gat_att = (const float*)d_in[10];
    const float* hattr   = (const float*)d_in[11];
    const float* lin_w   = (const float*)d_in[12];
    float* out = (float*)d_out;

    float* ws   = (float*)d_ws;
    float* umed = ws;                 // 1024
    float* uc   = umed + M_N;         // 512
    float* v    = uc + D_N;           // 512
    float* c1f  = v + D_N;            // 512
    float* c2f  = c1f + D_N;          // 512
    float* pp   = c2f + D_N;          // 192*64
    float* e1p  = pp + 192 * 64;      // 64*64
    float* e2p  = e1p + 64 * 64;      // 64*64
    float* e1dp = e2p + 64 * 64;      // 64*64
    float* e2dp = e1dp + 64 * 64;     // 64*64

    kprep<<<128, 512, 0, stream>>>(c_it, m_it, c_emb, m_emb, pe0, pe1,
                                   gat_w, gat_att, hattr, umed, uc, v, pp);
    kedge<<<64, 512, 0, stream>>>(c_it, c_emb, umed, uc, v,
                                  c1f, c2f, e1dp, e2dp);
    kmed<<<64, 512, 0, stream>>>(m_it, m_emb, umed, v, c1f, c2f, e1p, e2p);
    kfin<<<1, 512, 0, stream>>>(conv_w, conv_b, gat_w, gat_b, lin_w,
                                pp, e1p, e2p, e1dp, e2dp, out);
}

// Round 14
// 22.665 us; speedup vs baseline: 2.6917x; 1.0491x over previous
//
#include <hip/hip_runtime.h>
#include <hip/hip_bf16.h>

#define D_N 512
#define M_N 1024
#define F_N 64
#define L2E 1.442695041f

__device__ __forceinline__ float wred_sum(float p) {
#pragma unroll
    for (int off = 32; off > 0; off >>= 1) p += __shfl_xor(p, off, 64);
    return p;
}

// q[lane] = sum_k att[k] * W[k][lane]  (one wave)
__device__ __forceinline__ float proj_col(const float* __restrict__ gw,
                                          const float* __restrict__ att,
                                          int lane) {
    float acc = 0.f;
#pragma unroll
    for (int k = 0; k < 64; ++k)
        acc += att[k] * gw[k * 64 + lane];
    return acc;
}

// ---------------------------------------------------------------------------
// n1 kprep (128 blocks x 512): 2 rows per wave
//  b 0..31  : c-gathers rows [b*16,+16): pp P0[b], MC[32+b]; uc dots
//  b 32..95 : m-gathers rows [(b-32)*16,+16): pp P1[64+g2], MM[128+g2]; umed dots
//  b 96..127: hattr dots -> v
//  pp layout: P0 [0,32) MC [32,64) P1 [64,128) MM [128,192)
// ---------------------------------------------------------------------------
__global__ __launch_bounds__(512) void kprep(
    const int* __restrict__ c_it, const int* __restrict__ m_it,
    const float* __restrict__ c_emb, const float* __restrict__ m_emb,
    const float* __restrict__ pe0, const float* __restrict__ pe1,
    const float* __restrict__ gat_w, const float* __restrict__ gat_att,
    const float* __restrict__ hattr,
    float* __restrict__ umed, float* __restrict__ uc, float* __restrict__ v,
    float* __restrict__ pp)
{
    __shared__ __align__(16) float qs[64];
    __shared__ float redA[8][64], redB[8][64];
    const int b = blockIdx.x, tid = threadIdx.x;
    const int w = tid >> 6, lane = tid & 63;

    if (b < 96) {
        if (w == 0) qs[lane] = proj_col(gat_w, gat_att, lane);   // q1
        __syncthreads();
        const int* idx; const float* ta; const float* tb;
        float* dout; int base_r, oA, oB;
        if (b < 32) { idx = c_it; ta = pe0; tb = c_emb; dout = uc;
                      base_r = b * 16; oA = b; oB = 32 + b; }
        else { int g2 = b - 32; idx = m_it; ta = pe1; tb = m_emb; dout = umed;
               base_r = g2 * 16; oA = 64 + g2; oB = 128 + g2; }
        const int r0 = base_r + w * 2;
        const int ra = idx[r0], rb = idx[r0 + 1];
        const float ta0 = ta[(size_t)ra * F_N + lane];
        const float tb0 = tb[(size_t)ra * F_N + lane];
        const float ta1 = ta[(size_t)rb * F_N + lane];
        const float tb1 = tb[(size_t)rb * F_N + lane];
        float d0 = wred_sum(tb0 * qs[lane]);
        float d1 = wred_sum(tb1 * qs[lane]);
        if (lane == 0) { dout[r0] = L2E * d0; dout[r0 + 1] = L2E * d1; }
        redA[w][lane] = ta0 + ta1; redB[w][lane] = tb0 + tb1;
        __syncthreads();
        if (w == 0) {
            float sa = 0.f, sbv = 0.f;
#pragma unroll
            for (int i = 0; i < 8; ++i) { sa += redA[i][lane]; sbv += redB[i][lane]; }
            pp[oA * 64 + lane] = sa;
            pp[oB * 64 + lane] = sbv;
        }
    } else {
        if (w == 0) qs[lane] = proj_col(gat_w, gat_att + 64, lane);  // q2
        __syncthreads();
        const int r0 = (b - 96) * 16 + w * 2;
        const float h0 = hattr[(size_t)r0 * F_N + lane];
        const float h1 = hattr[(size_t)(r0 + 1) * F_N + lane];
        float d0 = wred_sum(h0 * qs[lane]);
        float d1 = wred_sum(h1 * qs[lane]);
        if (lane == 0) { v[r0] = L2E * d0; v[r0 + 1] = L2E * d1; }
    }
}

// ---------------------------------------------------------------------------
// n2 kedge (64 blocks x 512): ONE edge per wave; no LDS staging, no barrier
//  before the reduce. Direct coalesced L2 reads of umed.
// ---------------------------------------------------------------------------
__global__ __launch_bounds__(512) void kedge(
    const int* __restrict__ c_it, const float* __restrict__ c_emb,
    const float* __restrict__ umed_g, const float* __restrict__ uc,
    const float* __restrict__ v,
    float* __restrict__ c1f, float* __restrict__ c2f,
    float* __restrict__ e1dp, float* __restrict__ e2dp)
{
    __shared__ float redA[8][64], redB[8][64];
    const int b = blockIdx.x, tid = threadIdx.x;
    const int w = tid >> 6, lane = tid & 63;

    const int e = b * 8 + w;
    const float ve = v[e];
    const float uce = uc[e];
    const float xe = c_emb[(size_t)c_it[e] * F_N + lane];

    float s = 0.f;
#pragma unroll
    for (int i = 0; i < 16; ++i) {
        float a = umed_g[i * 64 + lane] + ve;
        a = fmaxf(a, 0.2f * a);
        s += exp2f(a);
    }
    s = wred_sum(s);
    float asf = uce + ve; asf = fmaxf(asf, 0.2f * asf);
    const float exs = exp2f(asf);
    const float denom = s + exs;
    const float asel = exs / denom;
    const float rd = 1.f / (denom * (float)(M_N + 1));
    if (lane == 0) {
        c1f[e] = asel * rd;
        c2f[e] = (1.f - asel) * rd;
    }
    redA[w][lane] = (asel * rd * exs) * xe;
    redB[w][lane] = ((1.f - asel) * rd * exs) * xe;
    __syncthreads();
    if (w == 0) {
        float sa = 0.f, sbv = 0.f;
#pragma unroll
        for (int i = 0; i < 8; ++i) { sa += redA[i][lane]; sbv += redB[i][lane]; }
        e1dp[b * 64 + lane] = sa;
        e2dp[b * 64 + lane] = sbv;
    }
}

// ---------------------------------------------------------------------------
// n3 kmed (64 blocks x 512): 16 meds/block, 32 threads/med; m_emb rows
//  prefetched to registers before the g-loop.
// ---------------------------------------------------------------------------
__global__ __launch_bounds__(512) void kmed(
    const int* __restrict__ m_it, const float* __restrict__ m_emb,
    const float* __restrict__ umed_g, const float* __restrict__ v,
    const float* __restrict__ c1f, const float* __restrict__ c2f,
    float* __restrict__ e1p, float* __restrict__ e2p)
{
    __shared__ float sV[D_N], sC1[D_N], sC2[D_N];
    __shared__ float sUm[16], sG1[16], sG2[16];
    __shared__ float redA[8][64], redB[8][64];
    const int b = blockIdx.x, tid = threadIdx.x;
    const int w = tid >> 6, lane = tid & 63;
    const int m_base = b * 16;

    // prefetch this wave's two output rows (independent of g-loop)
    const int ml0 = w * 2, ml1 = w * 2 + 1;
    const float x0 = m_emb[(size_t)m_it[m_base + ml0] * F_N + lane];
    const float x1 = m_emb[(size_t)m_it[m_base + ml1] * F_N + lane];

    sV[tid] = v[tid]; sC1[tid] = c1f[tid]; sC2[tid] = c2f[tid];
    if (tid < 16) sUm[tid] = umed_g[m_base + tid];
    __syncthreads();

    {
        const int mi = tid >> 5, l32 = tid & 31;
        const float um = sUm[mi];
        float gA = 0.f, gB = 0.f;
#pragma unroll 4
        for (int i = 0; i < 16; ++i) {
            int e = l32 + i * 32;
            float a = um + sV[e];
            a = fmaxf(a, 0.2f * a);
            float ex = exp2f(a);
            gA += sC1[e] * ex;
            gB += sC2[e] * ex;
        }
#pragma unroll
        for (int off = 1; off < 32; off <<= 1) {
            gA += __shfl_xor(gA, off, 64);
            gB += __shfl_xor(gB, off, 64);
        }
        if (l32 == 0) { sG1[mi] = gA; sG2[mi] = gB; }
    }
    __syncthreads();
    redA[w][lane] = sG1[ml0] * x0 + sG1[ml1] * x1;
    redB[w][lane] = sG2[ml0] * x0 + sG2[ml1] * x1;
    __syncthreads();
    if (w == 0) {
        float sa = 0.f, sbv = 0.f;
#pragma unroll
        for (int i = 0; i < 8; ++i) { sa += redA[i][lane]; sbv += redB[i][lane]; }
        e1p[b * 64 + lane] = sa;
        e2p[b * 64 + lane] = sbv;
    }
}

// ---------------------------------------------------------------------------
// n4 kfin (1 block x 512): round-robin folds (8 waves, independent loads),
//  3 weight matrices loaded concurrently, 3 barriers total.
//  Fold targets: T0 e1p(64) T1 e1dp(64) T2 e2p(64) T3 e2dp(64)
//                T4 P0(32)  T5 MC(32)   T6 P1(64)  T7 MM(64)
// ---------------------------------------------------------------------------
__global__ __launch_bounds__(512) void kfin(
    const float* __restrict__ conv_w, const float* __restrict__ conv_b,
    const float* __restrict__ gat_w, const float* __restrict__ gat_b,
    const float* __restrict__ lin_w,
    const float* __restrict__ pp,
    const float* __restrict__ e1p, const float* __restrict__ e2p,
    const float* __restrict__ e1dp, const float* __restrict__ e2dp,
    float* __restrict__ out)
{
    __shared__ float pA8[8][8][64];
    __shared__ float sE1[64], sE2[64], sP0[64], sP1[64], sMC[64], sMM[64];
    __shared__ float sS1[64], sS2[64], sDia[64], sMed[64];
    __shared__ float sRepD[128], sRepM[128];
    __shared__ float sWt[64 * 65];     // gat_w^T
    __shared__ float sCt[64 * 65];     // conv_w^T
    __shared__ float sLt[128 * 65];    // lin_w^T
    const int tid = threadIdx.x, w = tid >> 6, lane = tid & 63;

    // ---- phase A: round-robin folds (56 independent loads/wave) + matrix loads
    {
        float a0 = 0.f, a1 = 0.f, a2 = 0.f, a3 = 0.f;
        float a4 = 0.f, a5 = 0.f, a6 = 0.f, a7 = 0.f;
#pragma unroll
        for (int k = 0; k < 8; ++k) {
            const int i = w + 8 * k;
            a0 += e1p[i * 64 + lane];
            a1 += e1dp[i * 64 + lane];
            a2 += e2p[i * 64 + lane];
            a3 += e2dp[i * 64 + lane];
            a6 += pp[(64 + i) * 64 + lane];
            a7 += pp[(128 + i) * 64 + lane];
        }
#pragma unroll
        for (int k = 0; k < 4; ++k) {
            const int i = w + 8 * k;
            a4 += pp[i * 64 + lane];
            a5 += pp[(32 + i) * 64 + lane];
        }
        pA8[0][w][lane] = a0; pA8[1][w][lane] = a1;
        pA8[2][w][lane] = a2; pA8[3][w][lane] = a3;
        pA8[4][w][lane] = a4; pA8[5][w][lane] = a5;
        pA8[6][w][lane] = a6; pA8[7][w][lane] = a7;
    }
    for (int i = tid; i < 4096; i += 512) {
        sWt[(i & 63) * 65 + (i >> 6)] = gat_w[i];          // sWt[j*65+k]=W[k][j]
        sCt[(i & 63) * 65 + (i >> 6)] = conv_w[i];
    }
    for (int i = tid; i < 8192; i += 512) {
        int k = i >> 7, j = i & 127;
        sLt[j * 65 + k] = lin_w[i];                        // sLt[j*65+k]=lin_w[k][j]
    }
    __syncthreads();

    // ---- phase B: combine fold partials (waves 0..5) ----
    if (w == 0) {
        float a = 0.f;
#pragma unroll
        for (int j = 0; j < 8; ++j) a += pA8[0][j][lane] + pA8[1][j][lane];
        sE1[lane] = a;
    } else if (w == 1) {
        float a = 0.f;
#pragma unroll
        for (int j = 0; j < 8; ++j) a += pA8[2][j][lane] + pA8[3][j][lane];
        sE2[lane] = a;
    } else if (w == 2) {
        float a = 0.f;
#pragma unroll
        for (int j = 0; j < 8; ++j) a += pA8[4][j][lane];
        sP0[lane] = a;
    } else if (w == 3) {
        float a = 0.f;
#pragma unroll
        for (int j = 0; j < 8; ++j) a += pA8[5][j][lane];
        sMC[lane] = a * (1.f / (float)D_N);
    } else if (w == 4) {
        float a = 0.f;
#pragma unroll
        for (int j = 0; j < 8; ++j) a += pA8[6][j][lane];
        sP1[lane] = a;
    } else if (w == 5) {
        float a = 0.f;
#pragma unroll
        for (int j = 0; j < 8; ++j) a += pA8[7][j][lane];
        sMM[lane] = a * (1.f / (float)M_N);
    }
    __syncthreads();

    // ---- phase C: two matvecs in parallel (wave 0: S; wave 1: conv) ----
    if (w == 0) {
        float s1 = 0.f, s2 = 0.f;
#pragma unroll 8
        for (int j = 0; j < 64; ++j) {
            s1 += sE1[j] * sWt[j * 65 + lane];
            s2 += sE2[j] * sWt[j * 65 + lane];
        }
        sS1[lane] = s1;
        sS2[lane] = s2 * (1.f / (float)D_N);
    } else if (w == 1) {
        float dia = conv_b[lane], med = conv_b[lane];
#pragma unroll 8
        for (int j = 0; j < 64; ++j) {
            dia += sMC[j] * sCt[j * 65 + lane];
            med += sMM[j] * sCt[j * 65 + lane];
        }
        sDia[lane] = dia; sMed[lane] = med;
    }
    __syncthreads();

    // ---- phase D (wave 0, wave-synchronous): assemble rep + final matvec ----
    if (w == 0) {
        sRepD[lane]      = sS1[lane] + (float)D_N * gat_b[lane];
        sRepD[64 + lane] = (float)D_N * sDia[lane];
        sRepM[lane]      = sS2[lane] + (float)M_N * gat_b[lane];
        sRepM[64 + lane] = (float)M_N * sMed[lane];
        float o1 = sP0[lane], o2 = sP1[lane];
#pragma unroll 8
        for (int j = 0; j < 128; ++j) {
            o1 += sRepD[j] * sLt[j * 65 + lane];
            o2 += sRepM[j] * sLt[j * 65 + lane];
        }
        out[lane] = o1;
        out[64 + lane] = o2;
    }
}

extern "C" void kernel_launch(void* const* d_in, const int* in_sizes, int n_in,
                              void* d_out, int out_size, void* d_ws, size_t ws_size,
                              hipStream_t stream) {
    const int*   c_it    = (const int*)d_in[0];
    const int*   m_it    = (const int*)d_in[1];
    const float* c_emb   = (const float*)d_in[2];
    const float* m_emb   = (const float*)d_in[3];
    const float* pe0     = (const float*)d_in[4];
    const float* pe1     = (const float*)d_in[5];
    const float* conv_w  = (const float*)d_in[6];
    const float* conv_b  = (const float*)d_in[7];
    const float* gat_w   = (const float*)d_in[8];
    const float* gat_b   = (const float*)d_in[9];
    const float* gat_att = (const float*)d_in[10];
    const float* hattr   = (const float*)d_in[11];
    const float* lin_w   = (const float*)d_in[12];
    float* out = (float*)d_out;

    float* ws   = (float*)d_ws;
    float* umed = ws;                 // 1024
    float* uc   = umed + M_N;         // 512
    float* v    = uc + D_N;           // 512
    float* c1f  = v + D_N;            // 512
    float* c2f  = c1f + D_N;          // 512
    float* pp   = c2f + D_N;          // 192*64
    float* e1p  = pp + 192 * 64;      // 64*64
    float* e2p  = e1p + 64 * 64;      // 64*64
    float* e1dp = e2p + 64 * 64;      // 64*64
    float* e2dp = e1dp + 64 * 64;     // 64*64

    kprep<<<128, 512, 0, stream>>>(c_it, m_it, c_emb, m_emb, pe0, pe1,
                                   gat_w, gat_att, hattr, umed, uc, v, pp);
    kedge<<<64, 512, 0, stream>>>(c_it, c_emb, umed, uc, v,
                                  c1f, c2f, e1dp, e2dp);
    kmed<<<64, 512, 0, stream>>>(m_it, m_emb, umed, v, c1f, c2f, e1p, e2p);
    kfin<<<1, 512, 0, stream>>>(conv_w, conv_b, gat_w, gat_b, lin_w,
                                pp, e1p, e2p, e1dp, e2dp, out);
}